// Round 2
// baseline (798.979 us; speedup 1.0000x reference)
//
#include <hip/hip_runtime.h>
#include <hip/hip_bf16.h>

// Problem constants (fixed by the reference)
#define N_INST 262144
#define E_DIM  512
#define H_DIM  256
#define NBAGS  512
#define MI     32           // instances per tile
#define NBLOCKS 256         // persistent: 1 block per CU
#define TILES_PER_BLK (N_INST / MI / NBLOCKS)   // 32

typedef __bf16 bf16x8 __attribute__((ext_vector_type(8)));
typedef float  f32x4  __attribute__((ext_vector_type(4)));

__device__ __forceinline__ float fast_tanh(float x) {
    // tanh(x) = 1 - 2/(1+e^{2x}); amdgcn rcp ~1ulp, exp via v_exp_f32.
    float e = __expf(2.0f * x);
    return 1.0f - 2.0f * __builtin_amdgcn_rcpf(e + 1.0f);
}

// Async global->LDS DMA, 16B per lane. LDS dst is wave-uniform base + lane*16;
// the per-lane GLOBAL address carries the swizzle (both-sides-or-neither rule).
__device__ __forceinline__ void async_stage16(const float* g, float* l) {
    __builtin_amdgcn_global_load_lds(
        (const __attribute__((address_space(1))) void*)(const void*)g,
        (__attribute__((address_space(3))) void*)(void*)l,
        16, 0, 0);
}

// ---- prep: convert Vw fp32 -> bf16 (256x512)
__global__ void vw_to_bf16(const float* __restrict__ src,
                           __hip_bfloat16* __restrict__ dst) {
    int i = (blockIdx.x * 256 + threadIdx.x) * 4;
    float4 f = *(const float4*)(src + i);
    dst[i + 0] = __float2bfloat16(f.x);
    dst[i + 1] = __float2bfloat16(f.y);
    dst[i + 2] = __float2bfloat16(f.z);
    dst[i + 3] = __float2bfloat16(f.w);
}

// ---- persistent fused kernel. 8 waves; wave w owns H-cols [w*32, w*32+32).
// Vw B-fragments live in 128 VGPRs per lane for the whole kernel.
// X tiles are staged fp32 into LDS via global_load_lds with an XOR chunk
// swizzle: within a row, logical 16B-chunk c lives at physical chunk c^(row&7).
__global__ __launch_bounds__(512, 2) void attn_persist(
    const float* __restrict__ X,             // [N, E] fp32
    const __hip_bfloat16* __restrict__ Vw,   // [H, E] bf16
    const float* __restrict__ Vb,            // [H]
    const float* __restrict__ ww,            // [H]
    const float* __restrict__ wb,            // [1]
    const int* __restrict__ bidx,            // [N] sorted
    float* __restrict__ bag_acc,             // [NBAGS, E] fp32 (zeroed)
    float* __restrict__ sum_alphas)          // [NBAGS] fp32 (zeroed)
{
    __shared__ float xsb[2][MI * E_DIM];     // 131072 B, fp32 tiles (swizzled)
    __shared__ float s_part[8][MI];
    __shared__ float a_sh[MI];
    __shared__ int   bag_sh[2][MI];

    const int tid  = threadIdx.x;
    const int wave = tid >> 6;      // 0..7
    const int lane = tid & 63;
    const int l16  = lane & 15;
    const int kgrp = lane >> 4;     // 0..3
    const int sw   = l16 & 7;       // row&7 for this lane's A-rows (mt*16 doesn't touch low 3 bits)

    const int tile0 = blockIdx.x * TILES_PER_BLK;   // contiguous instance range

    // ---- load B-operand (this wave's 32 cols x all K) into registers, once
    bf16x8 breg[16][2];
    float ww_r[2], vb_r[2];
    {
        const __bf16* Vwp = (const __bf16*)Vw;
        #pragma unroll
        for (int nt = 0; nt < 2; nt++) {
            const int h = wave * 32 + nt * 16 + l16;
            ww_r[nt] = ww[h];
            vb_r[nt] = Vb[h];
            #pragma unroll
            for (int k = 0; k < 16; k++)
                breg[k][nt] = *(const bf16x8*)(Vwp + (size_t)h * E_DIM + k * 32 + kgrp * 8);
        }
    }

    // ---- prologue: async-stage tile 0 into xsb[0]
    // 64 DMA instructions per tile; wave w issues j=0..7, idx=w*8+j,
    // row r=idx>>1, half=idx&1 (each instruction covers half a row = 64 chunks).
    {
        const size_t i0 = (size_t)tile0 * MI;
        #pragma unroll
        for (int j = 0; j < 8; j++) {
            const int idx  = wave * 8 + j;
            const int r    = idx >> 1;
            const int half = idx & 1;
            const int c    = half * 64 + (lane ^ (r & 7));   // logical chunk for this lane
            async_stage16(X + (i0 + r) * E_DIM + c * 4,
                          &xsb[0][r * E_DIM + half * 256]);
        }
        if (tid < MI) bag_sh[0][tid] = bidx[i0 + tid];
    }
    asm volatile("s_waitcnt vmcnt(0)" ::: "memory");
    __builtin_amdgcn_sched_barrier(0);
    __syncthreads();

    // running per-bag accumulators (bags span tiles; bidx sorted)
    int   cur_bag = -1;
    float col_acc = 0.f;    // this thread's column (e = tid)
    float asum    = 0.f;
    const int colchunk = tid >> 2;   // 16B chunk of this thread's column
    const int colrem   = tid & 3;

    int p = 0;
    for (int it = 0; it < TILES_PER_BLK; it++) {
        const size_t inst0 = (size_t)(tile0 + it) * MI;
        const bool has_next = (it + 1 < TILES_PER_BLK);

        // (1) issue next tile's DMA into xsb[p^1] (free since last tile's B3)
        if (has_next) {
            const size_t i1 = inst0 + MI;
            #pragma unroll
            for (int j = 0; j < 8; j++) {
                const int idx  = wave * 8 + j;
                const int r    = idx >> 1;
                const int half = idx & 1;
                const int c    = half * 64 + (lane ^ (r & 7));
                async_stage16(X + (i1 + r) * E_DIM + c * 4,
                              &xsb[p ^ 1][r * E_DIM + half * 256]);
            }
            if (tid < MI) bag_sh[p ^ 1][tid] = bidx[i1 + tid];
        }

        // (2) GEMM on xsb[p] — fp32 LDS reads, convert to bf16 fragments in-reg
        f32x4 acc[2][2];
        #pragma unroll
        for (int mt = 0; mt < 2; mt++)
            #pragma unroll
            for (int nt = 0; nt < 2; nt++)
                acc[mt][nt] = (f32x4){0.f, 0.f, 0.f, 0.f};

        const float* xp = &xsb[p][0];
        #pragma unroll
        for (int k = 0; k < 16; k++) {
            const int c0 = k * 8 + kgrp * 2;          // logical chunk of this lane's 8 floats
            const int o0 = ((c0     ^ sw) << 2);      // physical float offset (swizzled)
            const int o1 = (((c0+1) ^ sw) << 2);
            bf16x8 afr[2];
            #pragma unroll
            for (int mt = 0; mt < 2; mt++) {
                const float* rowp = xp + (mt * 16 + l16) * E_DIM;
                f32x4 lo = *(const f32x4*)(rowp + o0);
                f32x4 hi = *(const f32x4*)(rowp + o1);
                bf16x8 fr;
                fr[0] = (__bf16)lo[0]; fr[1] = (__bf16)lo[1];
                fr[2] = (__bf16)lo[2]; fr[3] = (__bf16)lo[3];
                fr[4] = (__bf16)hi[0]; fr[5] = (__bf16)hi[1];
                fr[6] = (__bf16)hi[2]; fr[7] = (__bf16)hi[3];
                afr[mt] = fr;
            }
            #pragma unroll
            for (int mt = 0; mt < 2; mt++)
                #pragma unroll
                for (int nt = 0; nt < 2; nt++)
                    acc[mt][nt] = __builtin_amdgcn_mfma_f32_16x16x32_bf16(
                        afr[mt], breg[k][nt], acc[mt][nt], 0, 0, 0);
        }

        // (3) epilogue: v = tanh(acc+Vb); partial score = sum_h ww[h]*v
        #pragma unroll
        for (int mt = 0; mt < 2; mt++) {
            #pragma unroll
            for (int r = 0; r < 4; r++) {
                float t = 0.f;
                #pragma unroll
                for (int nt = 0; nt < 2; nt++)
                    t += ww_r[nt] * fast_tanh(acc[mt][nt][r] + vb_r[nt]);
                #pragma unroll
                for (int off = 1; off < 16; off <<= 1)
                    t += __shfl_xor(t, off, 64);
                if (l16 == 0)
                    s_part[wave][mt * 16 + kgrp * 4 + r] = t;
            }
        }
        __syncthreads();   // B1: s_part ready

        if (tid < MI) {
            float s = wb[0];
            #pragma unroll
            for (int w = 0; w < 8; w++) s += s_part[w][tid];
            a_sh[tid] = __expf(s);
        }
        __syncthreads();   // B2: a_sh ready

        // (4) segmented weighted accumulation; e = tid (one fp32 column/thread)
        for (int i = 0; i < MI; i++) {
            const int b = bag_sh[p][i];
            if (b != cur_bag) {
                if (cur_bag >= 0) {
                    atomicAdd(&bag_acc[(size_t)cur_bag * E_DIM + tid], col_acc);
                    if (tid == 0) atomicAdd(&sum_alphas[cur_bag], asum);
                }
                cur_bag = b; col_acc = 0.f; asum = 0.f;
            }
            const float a = a_sh[i];
            const float x = xp[i * E_DIM + ((colchunk ^ (i & 7)) << 2) + colrem];
            col_acc += a * x;
            asum    += a;
        }

        // (5) drain this tile's DMA (had GEMM+softmax+scan to land), reuse buffer
        asm volatile("s_waitcnt vmcnt(0)" ::: "memory");
        __builtin_amdgcn_sched_barrier(0);
        __syncthreads();   // B3: xsb[p^1]/bag_sh[p^1] complete; xsb[p] free
        p ^= 1;
    }

    // final flush
    if (cur_bag >= 0) {
        atomicAdd(&bag_acc[(size_t)cur_bag * E_DIM + tid], col_acc);
        if (tid == 0) atomicAdd(&sum_alphas[cur_bag], asum);
    }
}

// ---- finalize: bag_sum = acc/sum, logits = bag_sum . dw^T + db, softmax
__global__ void finalize(const float* __restrict__ bag_acc,
                         const float* __restrict__ sum_alphas,
                         const float* __restrict__ dw,
                         const float* __restrict__ db,
                         float* __restrict__ out) {
    const int b = blockIdx.x;
    const int lane = threadIdx.x;
    const float sa = sum_alphas[b];
    const float inv = (sa > 0.f) ? (1.f / sa) : 0.f;   // empty bag -> bag_sum 0
    float l0 = 0.f, l1 = 0.f;
    for (int e = lane; e < E_DIM; e += 64) {
        const float bs = bag_acc[(size_t)b * E_DIM + e] * inv;
        l0 += bs * dw[e];
        l1 += bs * dw[E_DIM + e];
    }
    for (int off = 32; off; off >>= 1) {
        l0 += __shfl_xor(l0, off, 64);
        l1 += __shfl_xor(l1, off, 64);
    }
    if (lane == 0) {
        l0 += db[0];
        l1 += db[1];
        const float m  = fmaxf(l0, l1);
        const float e0 = expf(l0 - m), e1 = expf(l1 - m);
        const float is = 1.f / (e0 + e1);
        out[b * 2 + 0] = e0 * is;
        out[b * 2 + 1] = e1 * is;
    }
}

extern "C" void kernel_launch(void* const* d_in, const int* in_sizes, int n_in,
                              void* d_out, int out_size, void* d_ws, size_t ws_size,
                              hipStream_t stream) {
    const float* X   = (const float*)d_in[0];  // bag_encoding [N,E]
    const float* Vwf = (const float*)d_in[1];  // [H,E]
    const float* Vb  = (const float*)d_in[2];  // [H]
    const float* ww  = (const float*)d_in[3];  // [1,H]
    const float* wb  = (const float*)d_in[4];  // [1]
    const float* dw  = (const float*)d_in[5];  // [2,E]
    const float* db  = (const float*)d_in[6];  // [2]
    const int*  bidx = (const int*)d_in[7];    // [N]
    float* out = (float*)d_out;

    // workspace layout: [Vw bf16: 256 KB][bag_acc: 1 MB][sum_alphas: 2 KB]
    __hip_bfloat16* Vwb = (__hip_bfloat16*)d_ws;
    float* bag_acc    = (float*)((char*)d_ws + (size_t)H_DIM * E_DIM * 2);
    float* sum_alphas = bag_acc + (size_t)NBAGS * E_DIM;

    hipMemsetAsync(bag_acc, 0, ((size_t)NBAGS * E_DIM + NBAGS) * sizeof(float), stream);
    vw_to_bf16<<<H_DIM * E_DIM / 1024, 256, 0, stream>>>(Vwf, Vwb);
    attn_persist<<<NBLOCKS, 512, 0, stream>>>(X, Vwb, Vb, ww, wb, bidx,
                                              bag_acc, sum_alphas);
    finalize<<<NBAGS, 64, 0, stream>>>(bag_acc, sum_alphas, dw, db, out);
}

// Round 3
// 769.296 us; speedup vs baseline: 1.0386x; 1.0386x over previous
//
#include <hip/hip_runtime.h>
#include <hip/hip_bf16.h>

// Problem constants (fixed by the reference)
#define N_INST 262144
#define E_DIM  512
#define H_DIM  256
#define NBAGS  512
#define MI     32           // instances per tile
#define XS_STRIDE 520       // bf16 elems per LDS row (+8 pad breaks bank aliasing)
#define NBLOCKS 256         // persistent: 1 block per CU
#define TILES_PER_BLK (N_INST / MI / NBLOCKS)   // 32

typedef __bf16 bf16x8 __attribute__((ext_vector_type(8)));
typedef float  f32x4  __attribute__((ext_vector_type(4)));

__device__ __forceinline__ float fast_tanh(float x) {
    // tanh(x) = 1 - 2/(1+e^{2x}); amdgcn rcp ~1ulp, exp via v_exp_f32.
    float e = __expf(2.0f * x);
    return 1.0f - 2.0f * __builtin_amdgcn_rcpf(e + 1.0f);
}

// ---- persistent fused kernel. 8 waves; wave w owns H-cols [w*32, w*32+32).
// Vw B-fragments are converted fp32->bf16 in-register at startup (L2-served;
// no prep kernel) and live in 128 VGPRs per lane for the whole kernel.
__global__ __launch_bounds__(512, 2) void attn_persist(
    const float* __restrict__ X,             // [N, E] fp32
    const float* __restrict__ Vw,            // [H, E] fp32
    const float* __restrict__ Vb,            // [H]
    const float* __restrict__ ww,            // [H]
    const float* __restrict__ wb,            // [1]
    const int* __restrict__ bidx,            // [N] sorted
    float* __restrict__ bag_acc,             // [NBAGS, E] fp32 (zeroed)
    float* __restrict__ sum_alphas)          // [NBAGS] fp32 (zeroed)
{
    __shared__ __hip_bfloat16 xs[2][MI][XS_STRIDE];  // 66560 B
    __shared__ float s_part[8][MI];
    __shared__ float a_sh[MI];
    __shared__ int   bag_sh[2][MI];

    const int tid  = threadIdx.x;
    const int wave = tid >> 6;      // 0..7
    const int lane = tid & 63;
    const int l16  = lane & 15;
    const int kgrp = lane >> 4;     // 0..3

    const int tile0 = blockIdx.x * TILES_PER_BLK;   // contiguous instance range

    // ---- load B-operand (this wave's 32 cols x all K) into registers, once.
    // Vw is fp32 in HBM; convert to bf16 fragments here (fused prep).
    bf16x8 breg[16][2];
    float ww_r[2], vb_r[2];
    {
        #pragma unroll
        for (int nt = 0; nt < 2; nt++) {
            const int h = wave * 32 + nt * 16 + l16;
            ww_r[nt] = ww[h];
            vb_r[nt] = Vb[h];
            const float* vrow = Vw + (size_t)h * E_DIM;
            #pragma unroll
            for (int k = 0; k < 16; k++) {
                f32x4 lo = *(const f32x4*)(vrow + k * 32 + kgrp * 8);
                f32x4 hi = *(const f32x4*)(vrow + k * 32 + kgrp * 8 + 4);
                bf16x8 fr;
                fr[0] = (__bf16)lo[0]; fr[1] = (__bf16)lo[1];
                fr[2] = (__bf16)lo[2]; fr[3] = (__bf16)lo[3];
                fr[4] = (__bf16)hi[0]; fr[5] = (__bf16)hi[1];
                fr[6] = (__bf16)hi[2]; fr[7] = (__bf16)hi[3];
                breg[k][nt] = fr;
            }
        }
    }

    // ---- stage-1 addressing: 512 threads, 8 float4/thread per tile
    const int c4 = tid & 127;       // float4 column 0..127
    const int r0 = tid >> 7;        // 0..3

    // prologue: stage tile 0 into xs[0]
    {
        const size_t i0 = (size_t)tile0 * MI;
        #pragma unroll
        for (int rr = 0; rr < 8; rr++) {
            const int r = rr * 4 + r0;
            float4 f = *(const float4*)(X + (i0 + r) * E_DIM + c4 * 4);
            __hip_bfloat16* dst = &xs[0][r][c4 * 4];
            dst[0] = __float2bfloat16(f.x);
            dst[1] = __float2bfloat16(f.y);
            dst[2] = __float2bfloat16(f.z);
            dst[3] = __float2bfloat16(f.w);
        }
        if (tid < MI) bag_sh[0][tid] = bidx[i0 + tid];
    }
    __syncthreads();

    // running per-bag accumulators (bags span tiles; bidx sorted)
    int   cur_bag = -1;
    float col_acc = 0.f;    // this thread's column (e = tid)
    float asum    = 0.f;

    int p = 0;
    for (int it = 0; it < TILES_PER_BLK; it++) {
        const size_t inst0 = (size_t)(tile0 + it) * MI;
        const bool has_next = (it + 1 < TILES_PER_BLK);

        // (1) issue next tile's global loads
        float4 ld[8];
        if (has_next) {
            const size_t i1 = inst0 + MI;
            #pragma unroll
            for (int rr = 0; rr < 8; rr++)
                ld[rr] = *(const float4*)(X + (i1 + rr * 4 + r0) * E_DIM + c4 * 4);
        }

        // (2) GEMM on xs[p] — pure LDS + register B
        f32x4 acc[2][2];
        #pragma unroll
        for (int mt = 0; mt < 2; mt++)
            #pragma unroll
            for (int nt = 0; nt < 2; nt++)
                acc[mt][nt] = (f32x4){0.f, 0.f, 0.f, 0.f};

        #pragma unroll
        for (int k = 0; k < 16; k++) {
            bf16x8 a_frag[2];
            #pragma unroll
            for (int mt = 0; mt < 2; mt++)
                a_frag[mt] = *(const bf16x8*)&xs[p][mt * 16 + l16][k * 32 + kgrp * 8];
            #pragma unroll
            for (int mt = 0; mt < 2; mt++)
                #pragma unroll
                for (int nt = 0; nt < 2; nt++)
                    acc[mt][nt] = __builtin_amdgcn_mfma_f32_16x16x32_bf16(
                        a_frag[mt], breg[k][nt], acc[mt][nt], 0, 0, 0);
        }

        // (3) drain next-tile loads -> bf16 -> xs[p^1] (hides HBM latency behind GEMM)
        if (has_next) {
            #pragma unroll
            for (int rr = 0; rr < 8; rr++) {
                const int r = rr * 4 + r0;
                __hip_bfloat16* dst = &xs[p ^ 1][r][c4 * 4];
                dst[0] = __float2bfloat16(ld[rr].x);
                dst[1] = __float2bfloat16(ld[rr].y);
                dst[2] = __float2bfloat16(ld[rr].z);
                dst[3] = __float2bfloat16(ld[rr].w);
            }
            if (tid < MI) bag_sh[p ^ 1][tid] = bidx[inst0 + MI + tid];
        }

        // (4) epilogue: v = tanh(acc+Vb); partial score = sum_h ww[h]*v
        #pragma unroll
        for (int mt = 0; mt < 2; mt++) {
            #pragma unroll
            for (int r = 0; r < 4; r++) {
                float t = 0.f;
                #pragma unroll
                for (int nt = 0; nt < 2; nt++)
                    t += ww_r[nt] * fast_tanh(acc[mt][nt][r] + vb_r[nt]);
                #pragma unroll
                for (int off = 1; off < 16; off <<= 1)
                    t += __shfl_xor(t, off, 64);
                if (l16 == 0)
                    s_part[wave][mt * 16 + kgrp * 4 + r] = t;
            }
        }
        __syncthreads();   // B1: s_part ready

        if (tid < MI) {
            float s = wb[0];
            #pragma unroll
            for (int w = 0; w < 8; w++) s += s_part[w][tid];
            a_sh[tid] = __expf(s);
        }
        __syncthreads();   // B2: a_sh ready

        // (5) segmented weighted accumulation; e = tid (one column/thread)
        for (int i = 0; i < MI; i++) {
            const int b = bag_sh[p][i];
            if (b != cur_bag) {
                if (cur_bag >= 0) {
                    atomicAdd(&bag_acc[(size_t)cur_bag * E_DIM + tid], col_acc);
                    if (tid == 0) atomicAdd(&sum_alphas[cur_bag], asum);
                }
                cur_bag = b; col_acc = 0.f; asum = 0.f;
            }
            const float a = a_sh[i];
            col_acc += a * __bfloat162float(xs[p][i][tid]);
            asum    += a;
        }
        __syncthreads();   // B3: xs[p^1]/bag_sh[p^1] complete; xs[p] free
        p ^= 1;
    }

    // final flush
    if (cur_bag >= 0) {
        atomicAdd(&bag_acc[(size_t)cur_bag * E_DIM + tid], col_acc);
        if (tid == 0) atomicAdd(&sum_alphas[cur_bag], asum);
    }
}

// ---- finalize: bag_sum = acc/sum, logits = bag_sum . dw^T + db, softmax
__global__ void finalize(const float* __restrict__ bag_acc,
                         const float* __restrict__ sum_alphas,
                         const float* __restrict__ dw,
                         const float* __restrict__ db,
                         float* __restrict__ out) {
    const int b = blockIdx.x;
    const int lane = threadIdx.x;
    const float sa = sum_alphas[b];
    const float inv = (sa > 0.f) ? (1.f / sa) : 0.f;   // empty bag -> bag_sum 0
    float l0 = 0.f, l1 = 0.f;
    for (int e = lane; e < E_DIM; e += 64) {
        const float bs = bag_acc[(size_t)b * E_DIM + e] * inv;
        l0 += bs * dw[e];
        l1 += bs * dw[E_DIM + e];
    }
    for (int off = 32; off; off >>= 1) {
        l0 += __shfl_xor(l0, off, 64);
        l1 += __shfl_xor(l1, off, 64);
    }
    if (lane == 0) {
        l0 += db[0];
        l1 += db[1];
        const float m  = fmaxf(l0, l1);
        const float e0 = expf(l0 - m), e1 = expf(l1 - m);
        const float is = 1.f / (e0 + e1);
        out[b * 2 + 0] = e0 * is;
        out[b * 2 + 1] = e1 * is;
    }
}

extern "C" void kernel_launch(void* const* d_in, const int* in_sizes, int n_in,
                              void* d_out, int out_size, void* d_ws, size_t ws_size,
                              hipStream_t stream) {
    const float* X   = (const float*)d_in[0];  // bag_encoding [N,E]
    const float* Vwf = (const float*)d_in[1];  // [H,E]
    const float* Vb  = (const float*)d_in[2];  // [H]
    const float* ww  = (const float*)d_in[3];  // [1,H]
    const float* wb  = (const float*)d_in[4];  // [1]
    const float* dw  = (const float*)d_in[5];  // [2,E]
    const float* db  = (const float*)d_in[6];  // [2]
    const int*  bidx = (const int*)d_in[7];    // [N]
    float* out = (float*)d_out;

    // workspace layout: [bag_acc: 1 MB][sum_alphas: 2 KB]
    float* bag_acc    = (float*)d_ws;
    float* sum_alphas = bag_acc + (size_t)NBAGS * E_DIM;

    hipMemsetAsync(bag_acc, 0, ((size_t)NBAGS * E_DIM + NBAGS) * sizeof(float), stream);
    attn_persist<<<NBLOCKS, 512, 0, stream>>>(X, Vwf, Vb, ww, wb, bidx,
                                              bag_acc, sum_alphas);
    finalize<<<NBAGS, 64, 0, stream>>>(bag_acc, sum_alphas, dw, db, out);
}

// Round 4
// 765.262 us; speedup vs baseline: 1.0441x; 1.0053x over previous
//
#include <hip/hip_runtime.h>
#include <hip/hip_bf16.h>

// Problem constants (fixed by the reference)
#define N_INST 262144
#define E_DIM  512
#define H_DIM  256
#define NBAGS  512
#define MI     32           // instances per tile
#define XS_STRIDE 520       // bf16 elems per LDS row (+8 pad breaks bank aliasing)
#define NBLOCKS 256         // persistent: 1 block per CU
#define TILES_PER_BLK (N_INST / MI / NBLOCKS)   // 32

typedef __bf16 bf16x8 __attribute__((ext_vector_type(8)));
typedef float  f32x4  __attribute__((ext_vector_type(4)));

__device__ __forceinline__ float fast_tanh(float x) {
    // tanh(x) = 1 - 2/(1+e^{2x}); amdgcn rcp ~1ulp, exp via v_exp_f32.
    float e = __expf(2.0f * x);
    return 1.0f - 2.0f * __builtin_amdgcn_rcpf(e + 1.0f);
}

// LDS-only barrier: drain LDS ops, then raw s_barrier. Unlike __syncthreads(),
// hipcc does NOT insert "s_waitcnt vmcnt(0)" here, so prefetched global loads
// stay in flight across the barrier (m97 stall avoided; T4 minimal form).
__device__ __forceinline__ void lds_barrier() {
    asm volatile("s_waitcnt lgkmcnt(0)" ::: "memory");
    __builtin_amdgcn_sched_barrier(0);
    __builtin_amdgcn_s_barrier();
}

// ---- prep: convert Vw fp32 -> bf16 (256x512) AND zero bag_acc/sum_alphas
// (fused memset saves one launch). 128 blocks x 256 threads.
__global__ void vw_to_bf16(const float* __restrict__ src,
                           __hip_bfloat16* __restrict__ dst,
                           float* __restrict__ zbase) {
    const int t = blockIdx.x * 256 + threadIdx.x;
    const int i = t * 4;
    float4 f = *(const float4*)(src + i);
    dst[i + 0] = __float2bfloat16(f.x);
    dst[i + 1] = __float2bfloat16(f.y);
    dst[i + 2] = __float2bfloat16(f.z);
    dst[i + 3] = __float2bfloat16(f.w);
    // zero bag_acc: 128*256 threads * 8 floats = 262144 = NBAGS*E_DIM
    const float4 z = {0.f, 0.f, 0.f, 0.f};
    *(float4*)(zbase + (size_t)t * 8)     = z;
    *(float4*)(zbase + (size_t)t * 8 + 4) = z;
    // zero sum_alphas (512 floats) right after bag_acc
    if (blockIdx.x == 0 && threadIdx.x < 128)
        *(float4*)(zbase + (size_t)NBAGS * E_DIM + threadIdx.x * 4) = z;
}

// ---- persistent fused kernel. 8 waves; wave w owns H-cols [w*32, w*32+32).
// Vw B-fragments live in 128 VGPRs per lane for the whole kernel.
__global__ __launch_bounds__(512, 2) void attn_persist(
    const float* __restrict__ X,             // [N, E] fp32
    const __hip_bfloat16* __restrict__ Vw,   // [H, E] bf16
    const float* __restrict__ Vb,            // [H]
    const float* __restrict__ ww,            // [H]
    const float* __restrict__ wb,            // [1]
    const int* __restrict__ bidx,            // [N] sorted
    float* __restrict__ bag_acc,             // [NBAGS, E] fp32 (zeroed)
    float* __restrict__ sum_alphas)          // [NBAGS] fp32 (zeroed)
{
    __shared__ __hip_bfloat16 xs[2][MI][XS_STRIDE];  // 66560 B
    __shared__ float s_part[8][MI];
    __shared__ float a_sh[MI];
    __shared__ int   bag_sh[2][MI];

    const int tid  = threadIdx.x;
    const int wave = tid >> 6;      // 0..7
    const int lane = tid & 63;
    const int l16  = lane & 15;
    const int kgrp = lane >> 4;     // 0..3

    const int tile0 = blockIdx.x * TILES_PER_BLK;   // contiguous instance range

    // ---- load B-operand (this wave's 32 cols x all K) into registers, once
    bf16x8 breg[16][2];
    float ww_r[2], vb_r[2];
    {
        const __bf16* Vwp = (const __bf16*)Vw;
        #pragma unroll
        for (int nt = 0; nt < 2; nt++) {
            const int h = wave * 32 + nt * 16 + l16;
            ww_r[nt] = ww[h];
            vb_r[nt] = Vb[h];
            #pragma unroll
            for (int k = 0; k < 16; k++)
                breg[k][nt] = *(const bf16x8*)(Vwp + (size_t)h * E_DIM + k * 32 + kgrp * 8);
        }
    }

    // ---- stage-1 addressing: 512 threads, 8 float4/thread per tile
    const int c4 = tid & 127;       // float4 column 0..127
    const int r0 = tid >> 7;        // 0..3

    // prologue: stage tile 0 into xs[0]
    {
        const size_t i0 = (size_t)tile0 * MI;
        #pragma unroll
        for (int rr = 0; rr < 8; rr++) {
            const int r = rr * 4 + r0;
            float4 f = *(const float4*)(X + (i0 + r) * E_DIM + c4 * 4);
            __hip_bfloat16* dst = &xs[0][r][c4 * 4];
            dst[0] = __float2bfloat16(f.x);
            dst[1] = __float2bfloat16(f.y);
            dst[2] = __float2bfloat16(f.z);
            dst[3] = __float2bfloat16(f.w);
        }
        if (tid < MI) bag_sh[0][tid] = bidx[i0 + tid];
    }
    __syncthreads();

    // running per-bag accumulators (bags span tiles; bidx sorted)
    int   cur_bag = -1;
    float col_acc = 0.f;    // this thread's column (e = tid)
    float asum    = 0.f;

    int p = 0;
    for (int it = 0; it < TILES_PER_BLK; it++) {
        const size_t inst0 = (size_t)(tile0 + it) * MI;
        const bool has_next = (it + 1 < TILES_PER_BLK);

        // (1) issue next tile's global loads (stay in flight across the
        //     whole tile body — barriers below are LDS-only)
        float4 ld[8];
        if (has_next) {
            const size_t i1 = inst0 + MI;
            #pragma unroll
            for (int rr = 0; rr < 8; rr++)
                ld[rr] = *(const float4*)(X + (i1 + rr * 4 + r0) * E_DIM + c4 * 4);
        }

        // (2) GEMM on xs[p] — pure LDS + register B
        f32x4 acc[2][2];
        #pragma unroll
        for (int mt = 0; mt < 2; mt++)
            #pragma unroll
            for (int nt = 0; nt < 2; nt++)
                acc[mt][nt] = (f32x4){0.f, 0.f, 0.f, 0.f};

        #pragma unroll
        for (int k = 0; k < 16; k++) {
            bf16x8 a_frag[2];
            #pragma unroll
            for (int mt = 0; mt < 2; mt++)
                a_frag[mt] = *(const bf16x8*)&xs[p][mt * 16 + l16][k * 32 + kgrp * 8];
            #pragma unroll
            for (int mt = 0; mt < 2; mt++)
                #pragma unroll
                for (int nt = 0; nt < 2; nt++)
                    acc[mt][nt] = __builtin_amdgcn_mfma_f32_16x16x32_bf16(
                        a_frag[mt], breg[k][nt], acc[mt][nt], 0, 0, 0);
        }

        // (3) epilogue: v = tanh(acc+Vb); partial score = sum_h ww[h]*v
        #pragma unroll
        for (int mt = 0; mt < 2; mt++) {
            #pragma unroll
            for (int r = 0; r < 4; r++) {
                float t = 0.f;
                #pragma unroll
                for (int nt = 0; nt < 2; nt++)
                    t += ww_r[nt] * fast_tanh(acc[mt][nt][r] + vb_r[nt]);
                #pragma unroll
                for (int off = 1; off < 16; off <<= 1)
                    t += __shfl_xor(t, off, 64);
                if (l16 == 0)
                    s_part[wave][mt * 16 + kgrp * 4 + r] = t;
            }
        }
        lds_barrier();   // B1: s_part ready (vmcnt NOT drained)

        if (tid < MI) {
            float s = wb[0];
            #pragma unroll
            for (int w = 0; w < 8; w++) s += s_part[w][tid];
            a_sh[tid] = __expf(s);
        }
        lds_barrier();   // B2: a_sh ready (vmcnt NOT drained)

        // (4) segmented weighted accumulation; e = tid (one column/thread)
        for (int i = 0; i < MI; i++) {
            const int b = bag_sh[p][i];
            if (b != cur_bag) {
                if (cur_bag >= 0) {
                    atomicAdd(&bag_acc[(size_t)cur_bag * E_DIM + tid], col_acc);
                    if (tid == 0) atomicAdd(&sum_alphas[cur_bag], asum);
                }
                cur_bag = b; col_acc = 0.f; asum = 0.f;
            }
            const float a = a_sh[i];
            col_acc += a * __bfloat162float(xs[p][i][tid]);
            asum    += a;
        }

        // (5) drain next-tile loads -> bf16 -> xs[p^1] (loads had GEMM +
        //     softmax + scan to complete; compiler inserts the vmcnt wait
        //     at first use of ld[])
        if (has_next) {
            #pragma unroll
            for (int rr = 0; rr < 8; rr++) {
                const int r = rr * 4 + r0;
                __hip_bfloat16* dst = &xs[p ^ 1][r][c4 * 4];
                dst[0] = __float2bfloat16(ld[rr].x);
                dst[1] = __float2bfloat16(ld[rr].y);
                dst[2] = __float2bfloat16(ld[rr].z);
                dst[3] = __float2bfloat16(ld[rr].w);
            }
            if (tid < MI) bag_sh[p ^ 1][tid] = bidx[inst0 + MI + tid];
        }
        lds_barrier();   // B3: xs[p^1]/bag_sh[p^1] complete; xs[p] free
        p ^= 1;
    }

    // final flush
    if (cur_bag >= 0) {
        atomicAdd(&bag_acc[(size_t)cur_bag * E_DIM + tid], col_acc);
        if (tid == 0) atomicAdd(&sum_alphas[cur_bag], asum);
    }
}

// ---- finalize: bag_sum = acc/sum, logits = bag_sum . dw^T + db, softmax
__global__ void finalize(const float* __restrict__ bag_acc,
                         const float* __restrict__ sum_alphas,
                         const float* __restrict__ dw,
                         const float* __restrict__ db,
                         float* __restrict__ out) {
    const int b = blockIdx.x;
    const int lane = threadIdx.x;
    const float sa = sum_alphas[b];
    const float inv = (sa > 0.f) ? (1.f / sa) : 0.f;   // empty bag -> bag_sum 0
    float l0 = 0.f, l1 = 0.f;
    for (int e = lane; e < E_DIM; e += 64) {
        const float bs = bag_acc[(size_t)b * E_DIM + e] * inv;
        l0 += bs * dw[e];
        l1 += bs * dw[E_DIM + e];
    }
    for (int off = 32; off; off >>= 1) {
        l0 += __shfl_xor(l0, off, 64);
        l1 += __shfl_xor(l1, off, 64);
    }
    if (lane == 0) {
        l0 += db[0];
        l1 += db[1];
        const float m  = fmaxf(l0, l1);
        const float e0 = expf(l0 - m), e1 = expf(l1 - m);
        const float is = 1.f / (e0 + e1);
        out[b * 2 + 0] = e0 * is;
        out[b * 2 + 1] = e1 * is;
    }
}

extern "C" void kernel_launch(void* const* d_in, const int* in_sizes, int n_in,
                              void* d_out, int out_size, void* d_ws, size_t ws_size,
                              hipStream_t stream) {
    const float* X   = (const float*)d_in[0];  // bag_encoding [N,E]
    const float* Vwf = (const float*)d_in[1];  // [H,E]
    const float* Vb  = (const float*)d_in[2];  // [H]
    const float* ww  = (const float*)d_in[3];  // [1,H]
    const float* wb  = (const float*)d_in[4];  // [1]
    const float* dw  = (const float*)d_in[5];  // [2,E]
    const float* db  = (const float*)d_in[6];  // [2]
    const int*  bidx = (const int*)d_in[7];    // [N]
    float* out = (float*)d_out;

    // workspace layout: [Vw bf16: 256 KB][bag_acc: 1 MB][sum_alphas: 2 KB]
    __hip_bfloat16* Vwb = (__hip_bfloat16*)d_ws;
    float* bag_acc    = (float*)((char*)d_ws + (size_t)H_DIM * E_DIM * 2);
    float* sum_alphas = bag_acc + (size_t)NBAGS * E_DIM;

    vw_to_bf16<<<H_DIM * E_DIM / 1024, 256, 0, stream>>>(Vwf, Vwb, bag_acc);
    attn_persist<<<NBLOCKS, 512, 0, stream>>>(X, Vwb, Vb, ww, wb, bidx,
                                              bag_acc, sum_alphas);
    finalize<<<NBAGS, 64, 0, stream>>>(bag_acc, sum_alphas, dw, db, out);
}